// Round 10
// baseline (342.840 us; speedup 1.0000x reference)
//
#include <hip/hip_runtime.h>
#include <hip/hip_bf16.h>
#include <stdint.h>

// PointNet EdgeConv, 2 layers. Round 24.
// R20: u32-packed descriptors, linear desc loads via shfl.     213 us
// R21: prep2 fused into layer-1 edge epilogue.                 211 us
// R22: manual SW-pipeline -> compiler scratch spill.           342 us
// R23: 64-dst ranges: edge 64->52us, Occ 38->44%.              204 us <- best
//      Occupancy capped by residency: EBS=512 allows only 4 blk/CU
//      (2048-thread cap) but NR=1563 needs 6.1/CU -> queueing + tail.
// R24: EBS=256 (4 waves/block). 8 blk/CU fit -> ALL 1563 blocks
//      resident from t=0 (no queue, variance averaged over ~6/CU,
//      2x independent gather chains). launch_bounds(256,8): VGPR cap
//      64 vs measured 40 -> no spill. Main loop & numerics identical.

#define BS 256
#define EBS 256        // edge kernel block size / chunk (256 edges, 4 waves)
#define K1_EDGES 4096  // edges staged per block in scatter pass
#define RB 64          // dsts per range

typedef float v2f __attribute__((ext_vector_type(2)));
typedef __attribute__((ext_vector_type(8))) short bf16x8;
typedef __attribute__((ext_vector_type(16))) float f32x16;
typedef __bf16 bf16v2 __attribute__((ext_vector_type(2)));

__device__ __forceinline__ unsigned ordenc(float f) {
    unsigned u = __float_as_uint(f);
    return (u & 0x80000000u) ? ~u : (u | 0x80000000u);
}
__device__ __forceinline__ float orddec(unsigned o) {
    unsigned u = (o & 0x80000000u) ? (o ^ 0x80000000u) : ~o;
    return __uint_as_float(u);
}
#define ORD_NEG_INF 0x007FFFFFu  // ordenc(-inf)
#define SRC_MASK 0xFFFFFu        // 20-bit src field (N < 1M)

// two f32 -> packed bf16 pair (RNE) via v_cvt_pk_bf16_f32; x -> low half
__device__ __forceinline__ unsigned cvt2(float x, float y) {
    v2f v = {x, y};
    bf16v2 b = __builtin_convertvector(v, bf16v2);
    return __builtin_bit_cast(unsigned, b);
}
__device__ __forceinline__ float bflo(unsigned u) { return __uint_as_float(u << 16); }
__device__ __forceinline__ float bfhi(unsigned u) { return __uint_as_float(u & 0xFFFF0000u); }

// build 8 channels of h = relu(bf16(U) - V) as 4 packed bf16 pairs
__device__ __forceinline__ uint4 mk_frag(uint4 ua, float4 v0, float4 v1) {
    uint4 o;
    o.x = cvt2(fmaxf(bflo(ua.x) - v0.x, 0.0f), fmaxf(bfhi(ua.x) - v0.y, 0.0f));
    o.y = cvt2(fmaxf(bflo(ua.y) - v0.z, 0.0f), fmaxf(bfhi(ua.y) - v0.w, 0.0f));
    o.z = cvt2(fmaxf(bflo(ua.z) - v1.x, 0.0f), fmaxf(bfhi(ua.z) - v1.y, 0.0f));
    o.w = cvt2(fmaxf(bflo(ua.w) - v1.z, 0.0f), fmaxf(bfhi(ua.w) - v1.w, 0.0f));
    return o;
}

// ---------------- fused setup: range-hist | prep1 | Wbt pack ----------------
__global__ __launch_bounds__(BS) void setup_kernel(
    const int* __restrict__ ei, int E, int NRP, int* __restrict__ blockHist,
    const float* __restrict__ pos, const float* __restrict__ Wa, const float* __restrict__ ba,
    unsigned* __restrict__ Ubf, float* __restrict__ V, int N, int NB1, int NBn,
    const float* __restrict__ Wb2, const float* __restrict__ Wb4,
    unsigned* __restrict__ WbtG) {
    __shared__ int hist[2048];
    const int tid = threadIdx.x;
    const int b = blockIdx.x;
    if (b < NB1) {
        for (int r = tid; r < 2048; r += BS) hist[r] = 0;
        __syncthreads();
        const int base = b * K1_EDGES;
        const int M = min(K1_EDGES, E - base);
        for (int i = tid; i < M; i += BS) atomicAdd(&hist[ei[E + base + i] >> 6], 1);
        __syncthreads();
        for (int r = tid; r < NRP; r += BS) blockHist[b * NRP + r] = hist[r];
    } else if (b < NB1 + NBn) {
        const int n = (b - NB1) * BS + tid;
        if (n >= N) return;
        const float p[3] = {pos[3 * n], pos[3 * n + 1], pos[3 * n + 2]};
        v2f u[16], v[16];
#pragma unroll
        for (int g = 0; g < 16; ++g) {
            u[g] = *reinterpret_cast<const v2f*>(&ba[g * 2]);
            v2f z = {0.0f, 0.0f};
            v[g] = z;
        }
#pragma unroll
        for (int i = 0; i < 3; ++i) {
            const v2f f = {p[i], p[i]};
#pragma unroll
            for (int g = 0; g < 16; ++g) {
                const v2f wA = *reinterpret_cast<const v2f*>(&Wa[i * 32 + g * 2]);
                const v2f wB = *reinterpret_cast<const v2f*>(&Wa[(i + 3) * 32 + g * 2]);
                u[g] = __builtin_elementwise_fma(f, wA + wB, u[g]);
                v[g] = __builtin_elementwise_fma(f, wB, v[g]);
            }
        }
        uint4* Up = reinterpret_cast<uint4*>(Ubf + (size_t)n * 16);
        float4* Vp = reinterpret_cast<float4*>(V + (size_t)n * 32);
#pragma unroll
        for (int q = 0; q < 4; ++q) {
            uint4 o;
            o.x = cvt2(u[4 * q + 0].x, u[4 * q + 0].y);
            o.y = cvt2(u[4 * q + 1].x, u[4 * q + 1].y);
            o.z = cvt2(u[4 * q + 2].x, u[4 * q + 2].y);
            o.w = cvt2(u[4 * q + 3].x, u[4 * q + 3].y);
            Up[q] = o;
        }
#pragma unroll
        for (int q = 0; q < 8; ++q)
            Vp[q] = make_float4(v[2 * q].x, v[2 * q].y, v[2 * q + 1].x, v[2 * q + 1].y);
    } else {
        // pack per-lane B fragments (bf16 pairs) for both layers: 2 x 512 dw
        if (tid < 128) {
            const int layer = tid >> 6;
            const int t = tid & 63;
            const int lnp = t & 31;
            const int hp = t >> 5;
            const float* Wb = layer ? Wb4 : Wb2;
            unsigned* dst = WbtG + layer * 512 + t * 8;
#pragma unroll
            for (int q = 0; q < 4; ++q) {
                const int p = 4 * hp + q;
                dst[q] = cvt2(Wb[(2 * p) * 32 + lnp], Wb[(2 * p + 1) * 32 + lnp]);
                dst[4 + q] = cvt2(Wb[(2 * p + 16) * 32 + lnp], Wb[(2 * p + 17) * 32 + lnp]);
            }
        }
    }
}

// ---------------- pass 2a: per-(block,range) LOCAL prefixes + range totals --
__global__ __launch_bounds__(512) void off_scan_kernel(const int* __restrict__ blockHist,
                                                       int NB1, int NRP,
                                                       int* __restrict__ off,
                                                       int* __restrict__ total) {
    const int r = (blockIdx.x * 512 + threadIdx.x) >> 6;
    const int lane = threadIdx.x & 63;
    if (r >= NRP) return;
    int carry = 0;
    const int chunks = (NB1 + 63) / 64;
    for (int c = 0; c < chunks; ++c) {
        const int b = c * 64 + lane;
        const int v = (b < NB1) ? blockHist[b * NRP + r] : 0;
        int x = v;
#pragma unroll
        for (int d = 1; d < 64; d <<= 1) {
            int y = __shfl_up(x, d, 64);
            if (lane >= d) x += y;
        }
        if (b < NB1) off[b * NRP + r] = carry + (x - v);
        carry += __shfl(x, 63, 64);
    }
    if (lane == 0) total[r] = carry;
}

// ---------------- pass 2b: exclusive scan of totals (<=2048) -> rangeBase ---
__global__ __launch_bounds__(1024) void range_scan_kernel(const int* __restrict__ total,
                                                          int NRP, int* __restrict__ rangeBase) {
    __shared__ int s[2048];
    const int t = threadIdx.x;
    const int v0 = (t < NRP) ? total[t] : 0;
    const int v1 = (t + 1024 < NRP) ? total[t + 1024] : 0;
    s[t] = v0;
    s[t + 1024] = v1;
    __syncthreads();
    for (int off = 1; off < 2048; off <<= 1) {
        const int a0 = (t >= off) ? s[t - off] : 0;
        const int a1 = (t + 1024 >= off) ? s[t + 1024 - off] : 0;
        __syncthreads();
        s[t] += a0;
        s[t + 1024] += a1;
        __syncthreads();
    }
    if (t < NRP) rangeBase[t] = s[t] - v0;
    if (t + 1024 < NRP) rangeBase[t + 1024] = s[t + 1024] - v1;
}

// ---------------- pass 1b: LDS-ranked scatter into range buckets ------------
// Stages u32-packed edges (src | dstLocal<<20) + u16 range ids.
__global__ __launch_bounds__(BS) void bucket_scatter_kernel(
    const int* __restrict__ ei, int E, int NRP, const int* __restrict__ off,
    const int* __restrict__ rangeBase, unsigned* __restrict__ sedgeB) {
    __shared__ unsigned stage[K1_EDGES];      // 16 KB
    __shared__ unsigned short rng[K1_EDGES];  // 8 KB
    __shared__ unsigned short inv[K1_EDGES];  // 8 KB
    __shared__ int hist[2048], start[2048], cursor[2048];  // 24 KB
    __shared__ int ts[BS];
    const int tid = threadIdx.x;
    for (int r = tid; r < 2048; r += BS) hist[r] = 0;
    __syncthreads();
    const int base = blockIdx.x * K1_EDGES;
    const int M = min(K1_EDGES, E - base);
    for (int i = tid; i < M; i += BS) {
        const int src = ei[base + i];
        const int dst = ei[E + base + i];
        const int r = dst >> 6;
        stage[i] = (unsigned)src | ((unsigned)(dst & 63) << 20);
        rng[i] = (unsigned short)r;
        atomicAdd(&hist[r], 1);
    }
    __syncthreads();
    {
        const int i0 = tid * 8;
        int lv[8];
        int tsum = 0;
#pragma unroll
        for (int k = 0; k < 8; ++k) {
            lv[k] = hist[i0 + k];
            tsum += lv[k];
        }
        ts[tid] = tsum;
        __syncthreads();
        for (int off2 = 1; off2 < BS; off2 <<= 1) {
            int add = (tid >= off2) ? ts[tid - off2] : 0;
            __syncthreads();
            ts[tid] += add;
            __syncthreads();
        }
        int run = ts[tid] - tsum;
#pragma unroll
        for (int k = 0; k < 8; ++k) {
            start[i0 + k] = run;
            cursor[i0 + k] = run;
            run += lv[k];
        }
    }
    __syncthreads();
    for (int i = tid; i < M; i += BS) {
        const int pos = atomicAdd(&cursor[rng[i]], 1);
        inv[pos] = (unsigned short)i;
    }
    __syncthreads();
    const int* offb = off + blockIdx.x * NRP;
    for (int j = tid; j < M; j += BS) {
        const int i = inv[j];
        const int r = rng[i];
        sedgeB[rangeBase[r] + offb[r] + (j - start[r])] = stage[i];  // contiguous runs
    }
}

// ---------------- range-bucket edge kernel (64-dst ranges, 4 waves) ---------
// MODE 0: final layer — decode aggL, relu, write float out.
// MODE 1: fused prep — compute layer-2 U/V for this block's 64 nodes.
// Main loop identical to R21/R23 (known no-spill codegen).
template <int MODE>
__global__ __launch_bounds__(EBS, 8) void edge_range_kernel(
    const unsigned* __restrict__ Ubf, const float4* __restrict__ V,
    const unsigned* __restrict__ sedgeB, const int* __restrict__ rangeBase,
    const int* __restrict__ total, const unsigned* __restrict__ WbtG,
    const float* __restrict__ bb, const float* __restrict__ pos,
    const float* __restrict__ Wa2, const float* __restrict__ ba2,
    unsigned* __restrict__ Ubf2, float* __restrict__ Vbuf2,
    float* __restrict__ out, int N) {
    __shared__ unsigned aggL[2048];             // [64 dst][32 ch], 8 KB
    __shared__ __align__(16) float4 vlds[576];  // [64 rows][9 f4] (8 used), 9 KB

    const int tid = threadIdx.x;
    const int r = blockIdx.x;
    const int base = rangeBase[r];
    const int M = total[r];
    const int last = M - 1;

    const int l = tid & 63;
    const int w = tid >> 6;  // 0..3: wave w owns chunk edges [64w, 64w+64)
    const int half = l >> 5;
    const int ln = l & 31;

#pragma unroll
    for (int i = 0; i < 8; ++i) aggL[tid + i * EBS] = ORD_NEG_INF;

    // stage V rows [64r, 64r+64): coalesced, padded stride 9
    {
        const float4* Vg = V + ((size_t)r << 9);        // row 64r, 8 f4/row
        const int vmax = min(512, (N - (r << 6)) * 8);  // clamp at N
        for (int j = tid; j < vmax; j += EBS) vlds[(j >> 3) * 9 + (j & 7)] = Vg[j];
    }

    // B fragments: precomputed per-lane packed bf16 (L1-hot, 2 loads)
    const uint4 bu0 = *reinterpret_cast<const uint4*>(WbtG + l * 8);
    const uint4 bu1 = *reinterpret_cast<const uint4*>(WbtG + l * 8 + 4);
    const float bbn = bb[ln];
    __syncthreads();  // aggL init + V stage visible

    const int nch = (M + EBS - 1) >> 8;
    unsigned pk = 0;
    if (64 * w < M) pk = sedgeB[base + min(64 * w + l, last)];  // chunk-0 descs
    for (int c = 0; c < nch; ++c) {
        // prefetch next chunk's descriptors (wave-uniform participation)
        unsigned npk = 0;
        const int ncb = (c + 1) << 8;
        const bool nextAct = (c + 1 < nch) && (ncb + 64 * w < M);
        if (nextAct) npk = sedgeB[base + min(ncb + 64 * w + l, last)];
        if ((c << 8) + 64 * w < M) {  // this wave active this chunk
            const unsigned pkA = __shfl(pk, ln, 64);       // edge cb+64w+ln
            const unsigned pkB = __shfl(pk, 32 + ln, 64);  // edge cb+64w+32+ln
            uint4 au00, au01, au10, au11;
            {
                const uint4* Up = reinterpret_cast<const uint4*>(Ubf + (size_t)(pkA & SRC_MASK) * 16);
                const float4* Vr = &vlds[(pkA >> 20) * 9];
                au00 = mk_frag(Up[half], Vr[2 * half], Vr[2 * half + 1]);
                au01 = mk_frag(Up[2 + half], Vr[4 + 2 * half], Vr[5 + 2 * half]);
            }
            {
                const uint4* Up = reinterpret_cast<const uint4*>(Ubf + (size_t)(pkB & SRC_MASK) * 16);
                const float4* Vr = &vlds[(pkB >> 20) * 9];
                au10 = mk_frag(Up[half], Vr[2 * half], Vr[2 * half + 1]);
                au11 = mk_frag(Up[2 + half], Vr[4 + 2 * half], Vr[5 + 2 * half]);
            }

            f32x16 c0, c1;
#pragma unroll
            for (int i = 0; i < 16; ++i) {
                c0[i] = bbn;
                c1[i] = bbn;
            }
            c0 = __builtin_amdgcn_mfma_f32_32x32x16_bf16(
                __builtin_bit_cast(bf16x8, au00), __builtin_bit_cast(bf16x8, bu0), c0, 0, 0, 0);
            c0 = __builtin_amdgcn_mfma_f32_32x32x16_bf16(
                __builtin_bit_cast(bf16x8, au01), __builtin_bit_cast(bf16x8, bu1), c0, 0, 0, 0);
            c1 = __builtin_amdgcn_mfma_f32_32x32x16_bf16(
                __builtin_bit_cast(bf16x8, au10), __builtin_bit_cast(bf16x8, bu0), c1, 0, 0, 0);
            c1 = __builtin_amdgcn_mfma_f32_32x32x16_bf16(
                __builtin_bit_cast(bf16x8, au11), __builtin_bit_cast(bf16x8, bu1), c1, 0, 0, 0);

            // scatter-max: C row rr <-> edge offset eo = (rr&3)+8(rr>>2)+4h;
            // edge cb+64w+eo held by lane eo (c0) / lane 32+eo (c1).
#pragma unroll
            for (int rr = 0; rr < 16; ++rr) {
                const int eo = (rr & 3) + 8 * (rr >> 2) + 4 * half;
                const int d0 = __shfl(pk, eo, 64) >> 20;
                const int d1 = __shfl(pk, 32 + eo, 64) >> 20;
                atomicMax(&aggL[(d0 << 5) | ln], ordenc(c0[rr]));
                atomicMax(&aggL[(d1 << 5) | ln], ordenc(c1[rr]));
            }
        }
        pk = npk;  // garbage if !nextAct, but then unused next iter
    }
    __syncthreads();

    if (MODE == 0) {
        // final writeout: 2048 values, 8 per thread, decode + relu -> float
        const int idx = tid * 8;
        const int node = (r << 6) + (idx >> 5);
        if (node < N) {
            float4 o0, o1;
            o0.x = fmaxf(orddec(aggL[idx + 0]), 0.0f);
            o0.y = fmaxf(orddec(aggL[idx + 1]), 0.0f);
            o0.z = fmaxf(orddec(aggL[idx + 2]), 0.0f);
            o0.w = fmaxf(orddec(aggL[idx + 3]), 0.0f);
            o1.x = fmaxf(orddec(aggL[idx + 4]), 0.0f);
            o1.y = fmaxf(orddec(aggL[idx + 5]), 0.0f);
            o1.z = fmaxf(orddec(aggL[idx + 6]), 0.0f);
            o1.w = fmaxf(orddec(aggL[idx + 7]), 0.0f);
            float4* op = reinterpret_cast<float4*>(out + (size_t)node * 32 + (idx & 31));
            op[0] = o0;
            op[1] = o1;
        }
    } else {
        // fused layer-2 prep: 4 threads per node, 8 channels each.
        const int node_l = tid >> 2;  // 0..63
        const int qq = tid & 3;       // channel group [8qq, 8qq+8)
        const int node = (r << 6) + node_l;
        if (node < N) {
            const unsigned* row = &aggL[node_l << 5];
            float h[32];
#pragma unroll
            for (int i = 0; i < 32; ++i) h[i] = fmaxf(orddec(row[i]), 0.0f);
            const float pp[3] = {pos[3 * node], pos[3 * node + 1], pos[3 * node + 2]};
            v2f u[4], v[4];
#pragma unroll
            for (int g = 0; g < 4; ++g) {
                u[g] = *reinterpret_cast<const v2f*>(&ba2[8 * qq + 2 * g]);
                v2f z = {0.0f, 0.0f};
                v[g] = z;
            }
#pragma unroll
            for (int i = 0; i < 32; ++i) {
                const v2f f = {h[i], h[i]};
#pragma unroll
                for (int g = 0; g < 4; ++g) {
                    const v2f wv =
                        *reinterpret_cast<const v2f*>(&Wa2[i * 32 + 8 * qq + 2 * g]);
                    u[g] = __builtin_elementwise_fma(f, wv, u[g]);
                }
            }
#pragma unroll
            for (int i = 0; i < 3; ++i) {
                const v2f f = {pp[i], pp[i]};
#pragma unroll
                for (int g = 0; g < 4; ++g) {
                    const v2f wv =
                        *reinterpret_cast<const v2f*>(&Wa2[(32 + i) * 32 + 8 * qq + 2 * g]);
                    u[g] = __builtin_elementwise_fma(f, wv, u[g]);
                    v[g] = __builtin_elementwise_fma(f, wv, v[g]);
                }
            }
            uint4 o;
            o.x = cvt2(u[0].x, u[0].y);
            o.y = cvt2(u[1].x, u[1].y);
            o.z = cvt2(u[2].x, u[2].y);
            o.w = cvt2(u[3].x, u[3].y);
            reinterpret_cast<uint4*>(Ubf2 + (size_t)node * 16)[qq] = o;
            float4* Vp = reinterpret_cast<float4*>(Vbuf2 + (size_t)node * 32 + 8 * qq);
            Vp[0] = make_float4(v[0].x, v[0].y, v[1].x, v[1].y);
            Vp[1] = make_float4(v[2].x, v[2].y, v[3].x, v[3].y);
        }
    }
}

extern "C" void kernel_launch(void* const* d_in, const int* in_sizes, int n_in,
                              void* d_out, int out_size, void* d_ws, size_t ws_size,
                              hipStream_t stream) {
    const float* pos = (const float*)d_in[0];
    const int* ei = (const int*)d_in[1];
    const float* W1 = (const float*)d_in[3];
    const float* b1 = (const float*)d_in[4];
    const float* W2 = (const float*)d_in[5];
    const float* b2 = (const float*)d_in[6];
    const float* W3 = (const float*)d_in[7];
    const float* b3 = (const float*)d_in[8];
    const float* W4 = (const float*)d_in[9];
    const float* b4 = (const float*)d_in[10];

    const int E = in_sizes[1] / 2;
    const int N = in_sizes[0] / 3;
    const int n32 = N * 32;
    const int NPAD = ((N + BS - 1) / BS) * BS;
    const int NR = (N + RB - 1) / RB;       // ranges of 64 dsts
    const int NRP = ((NR + 15) / 16) * 16;  // padded (<= 2048)
    const int NB1 = (E + K1_EDGES - 1) / K1_EDGES;
    const int BH = NB1 * NRP;

    int* blockHist = (int*)d_ws;                      // BH
    int* off = blockHist + BH;                        // BH
    int* total = off + BH;                            // NRP
    int* rangeBase = total + NRP;                     // NRP
    unsigned* sedgeB = (unsigned*)(rangeBase + NRP);  // E (u32-packed edges)
    unsigned* Ubf = (unsigned*)(sedgeB + E);          // NPAD*16 (layer-1 U)
    float* Vbuf = (float*)(Ubf + (size_t)NPAD * 16);  // n32 (layer-1 V)
    unsigned* Ubf2 = (unsigned*)(Vbuf + n32);         // NPAD*16 (layer-2 U)
    float* Vbuf2 = (float*)(Ubf2 + (size_t)NPAD * 16);  // n32 (layer-2 V)
    unsigned* WbtG = (unsigned*)(Vbuf2 + n32);        // 1024 dw (2 layers x 512)

    const int NBn = (N + BS - 1) / BS;

    // fused: hist | prep1 | Wbt pack (mutually independent)
    setup_kernel<<<NB1 + NBn + 1, BS, 0, stream>>>(ei, E, NRP, blockHist, pos, W1, b1, Ubf,
                                                   Vbuf, N, NB1, NBn, W2, W4, WbtG);
    off_scan_kernel<<<(NRP * 64 + 511) / 512, 512, 0, stream>>>(blockHist, NB1, NRP, off,
                                                                total);
    range_scan_kernel<<<1, 1024, 0, stream>>>(total, NRP, rangeBase);
    bucket_scatter_kernel<<<NB1, BS, 0, stream>>>(ei, E, NRP, off, rangeBase, sedgeB);

    // --- layer 1 (fused layer-2 prep in epilogue) ---
    edge_range_kernel<1><<<NR, EBS, 0, stream>>>(Ubf, (const float4*)Vbuf, sedgeB, rangeBase,
                                                 total, WbtG, b2, pos, W3, b3, Ubf2, Vbuf2,
                                                 nullptr, N);
    // --- layer 2 (final) ---
    edge_range_kernel<0><<<NR, EBS, 0, stream>>>(Ubf2, (const float4*)Vbuf2, sedgeB,
                                                 rangeBase, total, WbtG + 512, b4, nullptr,
                                                 nullptr, nullptr, nullptr, nullptr,
                                                 (float*)d_out, N);
}

// Round 11
// 209.611 us; speedup vs baseline: 1.6356x; 1.6356x over previous
//
#include <hip/hip_runtime.h>
#include <hip/hip_bf16.h>
#include <stdint.h>

// PointNet EdgeConv, 2 layers. Round 25.
// R21: prep2 fused into layer-1 edge epilogue.                 211 us
// R22: manual SW-pipeline -> compiler scratch spill.           342 us
// R23: 64-dst ranges: edge 64->52us, Occ 38->44%.              204 us <- best
// R24: EBS=256 + launch_bounds(256,8) -> SPILL #3.             342 us
//      Budget 512/8=64 regs on gfx950's UNIFIED VGPR/AGPR file;
//      c0+c1 accumulators = 32 AGPRs leave ~32 for the rest ->
//      scratch (VGPR_Count 32, WRITE 199MB). LOCKED RULE: this
//      main loop needs the >=85-reg budget => never request >6 waves/EU.
// R25: R24's idea with the proven budget: EBS=256 + launch_bounds(256,6).
//      6 blocks/CU resident (vs 4 at EBS=512); NR=1563 ~ 6.1x256 ->
//      whole grid resident from t=0; serial chains halved vs R23.
//      Main loop & numerics identical to R23.

#define BS 256
#define EBS 256        // edge kernel block size / chunk (256 edges, 4 waves)
#define K1_EDGES 4096  // edges staged per block in scatter pass
#define RB 64          // dsts per range

typedef float v2f __attribute__((ext_vector_type(2)));
typedef __attribute__((ext_vector_type(8))) short bf16x8;
typedef __attribute__((ext_vector_type(16))) float f32x16;
typedef __bf16 bf16v2 __attribute__((ext_vector_type(2)));

__device__ __forceinline__ unsigned ordenc(float f) {
    unsigned u = __float_as_uint(f);
    return (u & 0x80000000u) ? ~u : (u | 0x80000000u);
}
__device__ __forceinline__ float orddec(unsigned o) {
    unsigned u = (o & 0x80000000u) ? (o ^ 0x80000000u) : ~o;
    return __uint_as_float(u);
}
#define ORD_NEG_INF 0x007FFFFFu  // ordenc(-inf)
#define SRC_MASK 0xFFFFFu        // 20-bit src field (N < 1M)

// two f32 -> packed bf16 pair (RNE) via v_cvt_pk_bf16_f32; x -> low half
__device__ __forceinline__ unsigned cvt2(float x, float y) {
    v2f v = {x, y};
    bf16v2 b = __builtin_convertvector(v, bf16v2);
    return __builtin_bit_cast(unsigned, b);
}
__device__ __forceinline__ float bflo(unsigned u) { return __uint_as_float(u << 16); }
__device__ __forceinline__ float bfhi(unsigned u) { return __uint_as_float(u & 0xFFFF0000u); }

// build 8 channels of h = relu(bf16(U) - V) as 4 packed bf16 pairs
__device__ __forceinline__ uint4 mk_frag(uint4 ua, float4 v0, float4 v1) {
    uint4 o;
    o.x = cvt2(fmaxf(bflo(ua.x) - v0.x, 0.0f), fmaxf(bfhi(ua.x) - v0.y, 0.0f));
    o.y = cvt2(fmaxf(bflo(ua.y) - v0.z, 0.0f), fmaxf(bfhi(ua.y) - v0.w, 0.0f));
    o.z = cvt2(fmaxf(bflo(ua.z) - v1.x, 0.0f), fmaxf(bfhi(ua.z) - v1.y, 0.0f));
    o.w = cvt2(fmaxf(bflo(ua.w) - v1.z, 0.0f), fmaxf(bfhi(ua.w) - v1.w, 0.0f));
    return o;
}

// ---------------- fused setup: range-hist | prep1 | Wbt pack ----------------
__global__ __launch_bounds__(BS) void setup_kernel(
    const int* __restrict__ ei, int E, int NRP, int* __restrict__ blockHist,
    const float* __restrict__ pos, const float* __restrict__ Wa, const float* __restrict__ ba,
    unsigned* __restrict__ Ubf, float* __restrict__ V, int N, int NB1, int NBn,
    const float* __restrict__ Wb2, const float* __restrict__ Wb4,
    unsigned* __restrict__ WbtG) {
    __shared__ int hist[2048];
    const int tid = threadIdx.x;
    const int b = blockIdx.x;
    if (b < NB1) {
        for (int r = tid; r < 2048; r += BS) hist[r] = 0;
        __syncthreads();
        const int base = b * K1_EDGES;
        const int M = min(K1_EDGES, E - base);
        for (int i = tid; i < M; i += BS) atomicAdd(&hist[ei[E + base + i] >> 6], 1);
        __syncthreads();
        for (int r = tid; r < NRP; r += BS) blockHist[b * NRP + r] = hist[r];
    } else if (b < NB1 + NBn) {
        const int n = (b - NB1) * BS + tid;
        if (n >= N) return;
        const float p[3] = {pos[3 * n], pos[3 * n + 1], pos[3 * n + 2]};
        v2f u[16], v[16];
#pragma unroll
        for (int g = 0; g < 16; ++g) {
            u[g] = *reinterpret_cast<const v2f*>(&ba[g * 2]);
            v2f z = {0.0f, 0.0f};
            v[g] = z;
        }
#pragma unroll
        for (int i = 0; i < 3; ++i) {
            const v2f f = {p[i], p[i]};
#pragma unroll
            for (int g = 0; g < 16; ++g) {
                const v2f wA = *reinterpret_cast<const v2f*>(&Wa[i * 32 + g * 2]);
                const v2f wB = *reinterpret_cast<const v2f*>(&Wa[(i + 3) * 32 + g * 2]);
                u[g] = __builtin_elementwise_fma(f, wA + wB, u[g]);
                v[g] = __builtin_elementwise_fma(f, wB, v[g]);
            }
        }
        uint4* Up = reinterpret_cast<uint4*>(Ubf + (size_t)n * 16);
        float4* Vp = reinterpret_cast<float4*>(V + (size_t)n * 32);
#pragma unroll
        for (int q = 0; q < 4; ++q) {
            uint4 o;
            o.x = cvt2(u[4 * q + 0].x, u[4 * q + 0].y);
            o.y = cvt2(u[4 * q + 1].x, u[4 * q + 1].y);
            o.z = cvt2(u[4 * q + 2].x, u[4 * q + 2].y);
            o.w = cvt2(u[4 * q + 3].x, u[4 * q + 3].y);
            Up[q] = o;
        }
#pragma unroll
        for (int q = 0; q < 8; ++q)
            Vp[q] = make_float4(v[2 * q].x, v[2 * q].y, v[2 * q + 1].x, v[2 * q + 1].y);
    } else {
        // pack per-lane B fragments (bf16 pairs) for both layers: 2 x 512 dw
        if (tid < 128) {
            const int layer = tid >> 6;
            const int t = tid & 63;
            const int lnp = t & 31;
            const int hp = t >> 5;
            const float* Wb = layer ? Wb4 : Wb2;
            unsigned* dst = WbtG + layer * 512 + t * 8;
#pragma unroll
            for (int q = 0; q < 4; ++q) {
                const int p = 4 * hp + q;
                dst[q] = cvt2(Wb[(2 * p) * 32 + lnp], Wb[(2 * p + 1) * 32 + lnp]);
                dst[4 + q] = cvt2(Wb[(2 * p + 16) * 32 + lnp], Wb[(2 * p + 17) * 32 + lnp]);
            }
        }
    }
}

// ---------------- pass 2a: per-(block,range) LOCAL prefixes + range totals --
__global__ __launch_bounds__(512) void off_scan_kernel(const int* __restrict__ blockHist,
                                                       int NB1, int NRP,
                                                       int* __restrict__ off,
                                                       int* __restrict__ total) {
    const int r = (blockIdx.x * 512 + threadIdx.x) >> 6;
    const int lane = threadIdx.x & 63;
    if (r >= NRP) return;
    int carry = 0;
    const int chunks = (NB1 + 63) / 64;
    for (int c = 0; c < chunks; ++c) {
        const int b = c * 64 + lane;
        const int v = (b < NB1) ? blockHist[b * NRP + r] : 0;
        int x = v;
#pragma unroll
        for (int d = 1; d < 64; d <<= 1) {
            int y = __shfl_up(x, d, 64);
            if (lane >= d) x += y;
        }
        if (b < NB1) off[b * NRP + r] = carry + (x - v);
        carry += __shfl(x, 63, 64);
    }
    if (lane == 0) total[r] = carry;
}

// ---------------- pass 2b: exclusive scan of totals (<=2048) -> rangeBase ---
__global__ __launch_bounds__(1024) void range_scan_kernel(const int* __restrict__ total,
                                                          int NRP, int* __restrict__ rangeBase) {
    __shared__ int s[2048];
    const int t = threadIdx.x;
    const int v0 = (t < NRP) ? total[t] : 0;
    const int v1 = (t + 1024 < NRP) ? total[t + 1024] : 0;
    s[t] = v0;
    s[t + 1024] = v1;
    __syncthreads();
    for (int off = 1; off < 2048; off <<= 1) {
        const int a0 = (t >= off) ? s[t - off] : 0;
        const int a1 = (t + 1024 >= off) ? s[t + 1024 - off] : 0;
        __syncthreads();
        s[t] += a0;
        s[t + 1024] += a1;
        __syncthreads();
    }
    if (t < NRP) rangeBase[t] = s[t] - v0;
    if (t + 1024 < NRP) rangeBase[t + 1024] = s[t + 1024] - v1;
}

// ---------------- pass 1b: LDS-ranked scatter into range buckets ------------
// Stages u32-packed edges (src | dstLocal<<20) + u16 range ids.
__global__ __launch_bounds__(BS) void bucket_scatter_kernel(
    const int* __restrict__ ei, int E, int NRP, const int* __restrict__ off,
    const int* __restrict__ rangeBase, unsigned* __restrict__ sedgeB) {
    __shared__ unsigned stage[K1_EDGES];      // 16 KB
    __shared__ unsigned short rng[K1_EDGES];  // 8 KB
    __shared__ unsigned short inv[K1_EDGES];  // 8 KB
    __shared__ int hist[2048], start[2048], cursor[2048];  // 24 KB
    __shared__ int ts[BS];
    const int tid = threadIdx.x;
    for (int r = tid; r < 2048; r += BS) hist[r] = 0;
    __syncthreads();
    const int base = blockIdx.x * K1_EDGES;
    const int M = min(K1_EDGES, E - base);
    for (int i = tid; i < M; i += BS) {
        const int src = ei[base + i];
        const int dst = ei[E + base + i];
        const int r = dst >> 6;
        stage[i] = (unsigned)src | ((unsigned)(dst & 63) << 20);
        rng[i] = (unsigned short)r;
        atomicAdd(&hist[r], 1);
    }
    __syncthreads();
    {
        const int i0 = tid * 8;
        int lv[8];
        int tsum = 0;
#pragma unroll
        for (int k = 0; k < 8; ++k) {
            lv[k] = hist[i0 + k];
            tsum += lv[k];
        }
        ts[tid] = tsum;
        __syncthreads();
        for (int off2 = 1; off2 < BS; off2 <<= 1) {
            int add = (tid >= off2) ? ts[tid - off2] : 0;
            __syncthreads();
            ts[tid] += add;
            __syncthreads();
        }
        int run = ts[tid] - tsum;
#pragma unroll
        for (int k = 0; k < 8; ++k) {
            start[i0 + k] = run;
            cursor[i0 + k] = run;
            run += lv[k];
        }
    }
    __syncthreads();
    for (int i = tid; i < M; i += BS) {
        const int pos = atomicAdd(&cursor[rng[i]], 1);
        inv[pos] = (unsigned short)i;
    }
    __syncthreads();
    const int* offb = off + blockIdx.x * NRP;
    for (int j = tid; j < M; j += BS) {
        const int i = inv[j];
        const int r = rng[i];
        sedgeB[rangeBase[r] + offb[r] + (j - start[r])] = stage[i];  // contiguous runs
    }
}

// ---------------- range-bucket edge kernel (64-dst ranges, 4 waves) ---------
// MODE 0: final layer — decode aggL, relu, write float out.
// MODE 1: fused prep — compute layer-2 U/V for this block's 64 nodes.
// Main loop identical to R21/R23 (known no-spill codegen at the 85-reg
// budget — never request >6 waves/EU here).
template <int MODE>
__global__ __launch_bounds__(EBS, 6) void edge_range_kernel(
    const unsigned* __restrict__ Ubf, const float4* __restrict__ V,
    const unsigned* __restrict__ sedgeB, const int* __restrict__ rangeBase,
    const int* __restrict__ total, const unsigned* __restrict__ WbtG,
    const float* __restrict__ bb, const float* __restrict__ pos,
    const float* __restrict__ Wa2, const float* __restrict__ ba2,
    unsigned* __restrict__ Ubf2, float* __restrict__ Vbuf2,
    float* __restrict__ out, int N) {
    __shared__ unsigned aggL[2048];             // [64 dst][32 ch], 8 KB
    __shared__ __align__(16) float4 vlds[576];  // [64 rows][9 f4] (8 used), 9 KB

    const int tid = threadIdx.x;
    const int r = blockIdx.x;
    const int base = rangeBase[r];
    const int M = total[r];
    const int last = M - 1;

    const int l = tid & 63;
    const int w = tid >> 6;  // 0..3: wave w owns chunk edges [64w, 64w+64)
    const int half = l >> 5;
    const int ln = l & 31;

#pragma unroll
    for (int i = 0; i < 8; ++i) aggL[tid + i * EBS] = ORD_NEG_INF;

    // stage V rows [64r, 64r+64): coalesced, padded stride 9
    {
        const float4* Vg = V + ((size_t)r << 9);        // row 64r, 8 f4/row
        const int vmax = min(512, (N - (r << 6)) * 8);  // clamp at N
        for (int j = tid; j < vmax; j += EBS) vlds[(j >> 3) * 9 + (j & 7)] = Vg[j];
    }

    // B fragments: precomputed per-lane packed bf16 (L1-hot, 2 loads)
    const uint4 bu0 = *reinterpret_cast<const uint4*>(WbtG + l * 8);
    const uint4 bu1 = *reinterpret_cast<const uint4*>(WbtG + l * 8 + 4);
    const float bbn = bb[ln];
    __syncthreads();  // aggL init + V stage visible

    const int nch = (M + EBS - 1) >> 8;
    unsigned pk = 0;
    if (64 * w < M) pk = sedgeB[base + min(64 * w + l, last)];  // chunk-0 descs
    for (int c = 0; c < nch; ++c) {
        // prefetch next chunk's descriptors (wave-uniform participation)
        unsigned npk = 0;
        const int ncb = (c + 1) << 8;
        const bool nextAct = (c + 1 < nch) && (ncb + 64 * w < M);
        if (nextAct) npk = sedgeB[base + min(ncb + 64 * w + l, last)];
        if ((c << 8) + 64 * w < M) {  // this wave active this chunk
            const unsigned pkA = __shfl(pk, ln, 64);       // edge cb+64w+ln
            const unsigned pkB = __shfl(pk, 32 + ln, 64);  // edge cb+64w+32+ln
            uint4 au00, au01, au10, au11;
            {
                const uint4* Up = reinterpret_cast<const uint4*>(Ubf + (size_t)(pkA & SRC_MASK) * 16);
                const float4* Vr = &vlds[(pkA >> 20) * 9];
                au00 = mk_frag(Up[half], Vr[2 * half], Vr[2 * half + 1]);
                au01 = mk_frag(Up[2 + half], Vr[4 + 2 * half], Vr[5 + 2 * half]);
            }
            {
                const uint4* Up = reinterpret_cast<const uint4*>(Ubf + (size_t)(pkB & SRC_MASK) * 16);
                const float4* Vr = &vlds[(pkB >> 20) * 9];
                au10 = mk_frag(Up[half], Vr[2 * half], Vr[2 * half + 1]);
                au11 = mk_frag(Up[2 + half], Vr[4 + 2 * half], Vr[5 + 2 * half]);
            }

            f32x16 c0, c1;
#pragma unroll
            for (int i = 0; i < 16; ++i) {
                c0[i] = bbn;
                c1[i] = bbn;
            }
            c0 = __builtin_amdgcn_mfma_f32_32x32x16_bf16(
                __builtin_bit_cast(bf16x8, au00), __builtin_bit_cast(bf16x8, bu0), c0, 0, 0, 0);
            c0 = __builtin_amdgcn_mfma_f32_32x32x16_bf16(
                __builtin_bit_cast(bf16x8, au01), __builtin_bit_cast(bf16x8, bu1), c0, 0, 0, 0);
            c1 = __builtin_amdgcn_mfma_f32_32x32x16_bf16(
                __builtin_bit_cast(bf16x8, au10), __builtin_bit_cast(bf16x8, bu0), c1, 0, 0, 0);
            c1 = __builtin_amdgcn_mfma_f32_32x32x16_bf16(
                __builtin_bit_cast(bf16x8, au11), __builtin_bit_cast(bf16x8, bu1), c1, 0, 0, 0);

            // scatter-max: C row rr <-> edge offset eo = (rr&3)+8(rr>>2)+4h;
            // edge cb+64w+eo held by lane eo (c0) / lane 32+eo (c1).
#pragma unroll
            for (int rr = 0; rr < 16; ++rr) {
                const int eo = (rr & 3) + 8 * (rr >> 2) + 4 * half;
                const int d0 = __shfl(pk, eo, 64) >> 20;
                const int d1 = __shfl(pk, 32 + eo, 64) >> 20;
                atomicMax(&aggL[(d0 << 5) | ln], ordenc(c0[rr]));
                atomicMax(&aggL[(d1 << 5) | ln], ordenc(c1[rr]));
            }
        }
        pk = npk;  // garbage if !nextAct, but then unused next iter
    }
    __syncthreads();

    if (MODE == 0) {
        // final writeout: 2048 values, 8 per thread, decode + relu -> float
        const int idx = tid * 8;
        const int node = (r << 6) + (idx >> 5);
        if (node < N) {
            float4 o0, o1;
            o0.x = fmaxf(orddec(aggL[idx + 0]), 0.0f);
            o0.y = fmaxf(orddec(aggL[idx + 1]), 0.0f);
            o0.z = fmaxf(orddec(aggL[idx + 2]), 0.0f);
            o0.w = fmaxf(orddec(aggL[idx + 3]), 0.0f);
            o1.x = fmaxf(orddec(aggL[idx + 4]), 0.0f);
            o1.y = fmaxf(orddec(aggL[idx + 5]), 0.0f);
            o1.z = fmaxf(orddec(aggL[idx + 6]), 0.0f);
            o1.w = fmaxf(orddec(aggL[idx + 7]), 0.0f);
            float4* op = reinterpret_cast<float4*>(out + (size_t)node * 32 + (idx & 31));
            op[0] = o0;
            op[1] = o1;
        }
    } else {
        // fused layer-2 prep: 4 threads per node, 8 channels each.
        const int node_l = tid >> 2;  // 0..63
        const int qq = tid & 3;       // channel group [8qq, 8qq+8)
        const int node = (r << 6) + node_l;
        if (node < N) {
            const unsigned* row = &aggL[node_l << 5];
            float h[32];
#pragma unroll
            for (int i = 0; i < 32; ++i) h[i] = fmaxf(orddec(row[i]), 0.0f);
            const float pp[3] = {pos[3 * node], pos[3 * node + 1], pos[3 * node + 2]};
            v2f u[4], v[4];
#pragma unroll
            for (int g = 0; g < 4; ++g) {
                u[g] = *reinterpret_cast<const v2f*>(&ba2[8 * qq + 2 * g]);
                v2f z = {0.0f, 0.0f};
                v[g] = z;
            }
#pragma unroll
            for (int i = 0; i < 32; ++i) {
                const v2f f = {h[i], h[i]};
#pragma unroll
                for (int g = 0; g < 4; ++g) {
                    const v2f wv =
                        *reinterpret_cast<const v2f*>(&Wa2[i * 32 + 8 * qq + 2 * g]);
                    u[g] = __builtin_elementwise_fma(f, wv, u[g]);
                }
            }
#pragma unroll
            for (int i = 0; i < 3; ++i) {
                const v2f f = {pp[i], pp[i]};
#pragma unroll
                for (int g = 0; g < 4; ++g) {
                    const v2f wv =
                        *reinterpret_cast<const v2f*>(&Wa2[(32 + i) * 32 + 8 * qq + 2 * g]);
                    u[g] = __builtin_elementwise_fma(f, wv, u[g]);
                    v[g] = __builtin_elementwise_fma(f, wv, v[g]);
                }
            }
            uint4 o;
            o.x = cvt2(u[0].x, u[0].y);
            o.y = cvt2(u[1].x, u[1].y);
            o.z = cvt2(u[2].x, u[2].y);
            o.w = cvt2(u[3].x, u[3].y);
            reinterpret_cast<uint4*>(Ubf2 + (size_t)node * 16)[qq] = o;
            float4* Vp = reinterpret_cast<float4*>(Vbuf2 + (size_t)node * 32 + 8 * qq);
            Vp[0] = make_float4(v[0].x, v[0].y, v[1].x, v[1].y);
            Vp[1] = make_float4(v[2].x, v[2].y, v[3].x, v[3].y);
        }
    }
}

extern "C" void kernel_launch(void* const* d_in, const int* in_sizes, int n_in,
                              void* d_out, int out_size, void* d_ws, size_t ws_size,
                              hipStream_t stream) {
    const float* pos = (const float*)d_in[0];
    const int* ei = (const int*)d_in[1];
    const float* W1 = (const float*)d_in[3];
    const float* b1 = (const float*)d_in[4];
    const float* W2 = (const float*)d_in[5];
    const float* b2 = (const float*)d_in[6];
    const float* W3 = (const float*)d_in[7];
    const float* b3 = (const float*)d_in[8];
    const float* W4 = (const float*)d_in[9];
    const float* b4 = (const float*)d_in[10];

    const int E = in_sizes[1] / 2;
    const int N = in_sizes[0] / 3;
    const int n32 = N * 32;
    const int NPAD = ((N + BS - 1) / BS) * BS;
    const int NR = (N + RB - 1) / RB;       // ranges of 64 dsts
    const int NRP = ((NR + 15) / 16) * 16;  // padded (<= 2048)
    const int NB1 = (E + K1_EDGES - 1) / K1_EDGES;
    const int BH = NB1 * NRP;

    int* blockHist = (int*)d_ws;                      // BH
    int* off = blockHist + BH;                        // BH
    int* total = off + BH;                            // NRP
    int* rangeBase = total + NRP;                     // NRP
    unsigned* sedgeB = (unsigned*)(rangeBase + NRP);  // E (u32-packed edges)
    unsigned* Ubf = (unsigned*)(sedgeB + E);          // NPAD*16 (layer-1 U)
    float* Vbuf = (float*)(Ubf + (size_t)NPAD * 16);  // n32 (layer-1 V)
    unsigned* Ubf2 = (unsigned*)(Vbuf + n32);         // NPAD*16 (layer-2 U)
    float* Vbuf2 = (float*)(Ubf2 + (size_t)NPAD * 16);  // n32 (layer-2 V)
    unsigned* WbtG = (unsigned*)(Vbuf2 + n32);        // 1024 dw (2 layers x 512)

    const int NBn = (N + BS - 1) / BS;

    // fused: hist | prep1 | Wbt pack (mutually independent)
    setup_kernel<<<NB1 + NBn + 1, BS, 0, stream>>>(ei, E, NRP, blockHist, pos, W1, b1, Ubf,
                                                   Vbuf, N, NB1, NBn, W2, W4, WbtG);
    off_scan_kernel<<<(NRP * 64 + 511) / 512, 512, 0, stream>>>(blockHist, NB1, NRP, off,
                                                                total);
    range_scan_kernel<<<1, 1024, 0, stream>>>(total, NRP, rangeBase);
    bucket_scatter_kernel<<<NB1, BS, 0, stream>>>(ei, E, NRP, off, rangeBase, sedgeB);

    // --- layer 1 (fused layer-2 prep in epilogue) ---
    edge_range_kernel<1><<<NR, EBS, 0, stream>>>(Ubf, (const float4*)Vbuf, sedgeB, rangeBase,
                                                 total, WbtG, b2, pos, W3, b3, Ubf2, Vbuf2,
                                                 nullptr, N);
    // --- layer 2 (final) ---
    edge_range_kernel<0><<<NR, EBS, 0, stream>>>(Ubf2, (const float4*)Vbuf2, sedgeB,
                                                 rangeBase, total, WbtG + 512, b4, nullptr,
                                                 nullptr, nullptr, nullptr, nullptr,
                                                 (float*)d_out, N);
}

// Round 12
// 201.008 us; speedup vs baseline: 1.7056x; 1.0428x over previous
//
#include <hip/hip_runtime.h>
#include <hip/hip_bf16.h>
#include <stdint.h>

// PointNet EdgeConv, 2 layers. Round 26.
// R21: prep2 fused into layer-1 edge epilogue.                 211 us
// R23: 64-dst ranges, EBS=512, (512,6).                        204 us <- best
// R24: (256,8) -> SPILL #3 (unified VGPR/AGPR budget 64).      342 us
// R25: EBS=256 @ (256,6): per-wave chains DOUBLED (M/64/waves) 210 us
//      -> block-geometry knobs exhausted; R23 geometry is best.
// R26: R23 geometry + scatter-phase op-count cuts (per wave-chunk:
//      34 DS-shfl + 64 LDS atomics was the dominant LDS load):
//      * per-wave 64B dst byte table (R22-proven): 8 broadcast b32
//        reads replace 32 shfls.
//      * quad-collapsed atomics: rows 4g..4g+3 = CONSECUTIVE edges
//        (eo=8g+4h+j); dst word uniform per half-wave -> non-divergent
//        test; deg~16 => ~80% quads single-dst: 3 fmax + 1 ordenc +
//        1 atomicMax replace 4+4. Atomics/chunk 64 -> ~20.
//      max assoc. + ordenc monotonic => bit-identical results.

#define BS 256
#define EBS 512        // edge kernel block size / chunk (512 edges, 8 waves)
#define K1_EDGES 4096  // edges staged per block in scatter pass
#define RB 64          // dsts per range

typedef float v2f __attribute__((ext_vector_type(2)));
typedef __attribute__((ext_vector_type(8))) short bf16x8;
typedef __attribute__((ext_vector_type(16))) float f32x16;
typedef __bf16 bf16v2 __attribute__((ext_vector_type(2)));

__device__ __forceinline__ unsigned ordenc(float f) {
    unsigned u = __float_as_uint(f);
    return (u & 0x80000000u) ? ~u : (u | 0x80000000u);
}
__device__ __forceinline__ float orddec(unsigned o) {
    unsigned u = (o & 0x80000000u) ? (o ^ 0x80000000u) : ~o;
    return __uint_as_float(u);
}
#define ORD_NEG_INF 0x007FFFFFu  // ordenc(-inf)
#define SRC_MASK 0xFFFFFu        // 20-bit src field (N < 1M)

// two f32 -> packed bf16 pair (RNE) via v_cvt_pk_bf16_f32; x -> low half
__device__ __forceinline__ unsigned cvt2(float x, float y) {
    v2f v = {x, y};
    bf16v2 b = __builtin_convertvector(v, bf16v2);
    return __builtin_bit_cast(unsigned, b);
}
__device__ __forceinline__ float bflo(unsigned u) { return __uint_as_float(u << 16); }
__device__ __forceinline__ float bfhi(unsigned u) { return __uint_as_float(u & 0xFFFF0000u); }

// build 8 channels of h = relu(bf16(U) - V) as 4 packed bf16 pairs
__device__ __forceinline__ uint4 mk_frag(uint4 ua, float4 v0, float4 v1) {
    uint4 o;
    o.x = cvt2(fmaxf(bflo(ua.x) - v0.x, 0.0f), fmaxf(bfhi(ua.x) - v0.y, 0.0f));
    o.y = cvt2(fmaxf(bflo(ua.y) - v0.z, 0.0f), fmaxf(bfhi(ua.y) - v0.w, 0.0f));
    o.z = cvt2(fmaxf(bflo(ua.z) - v1.x, 0.0f), fmaxf(bfhi(ua.z) - v1.y, 0.0f));
    o.w = cvt2(fmaxf(bflo(ua.w) - v1.z, 0.0f), fmaxf(bfhi(ua.w) - v1.w, 0.0f));
    return o;
}

// ---------------- fused setup: range-hist | prep1 | Wbt pack ----------------
__global__ __launch_bounds__(BS) void setup_kernel(
    const int* __restrict__ ei, int E, int NRP, int* __restrict__ blockHist,
    const float* __restrict__ pos, const float* __restrict__ Wa, const float* __restrict__ ba,
    unsigned* __restrict__ Ubf, float* __restrict__ V, int N, int NB1, int NBn,
    const float* __restrict__ Wb2, const float* __restrict__ Wb4,
    unsigned* __restrict__ WbtG) {
    __shared__ int hist[2048];
    const int tid = threadIdx.x;
    const int b = blockIdx.x;
    if (b < NB1) {
        for (int r = tid; r < 2048; r += BS) hist[r] = 0;
        __syncthreads();
        const int base = b * K1_EDGES;
        const int M = min(K1_EDGES, E - base);
        for (int i = tid; i < M; i += BS) atomicAdd(&hist[ei[E + base + i] >> 6], 1);
        __syncthreads();
        for (int r = tid; r < NRP; r += BS) blockHist[b * NRP + r] = hist[r];
    } else if (b < NB1 + NBn) {
        const int n = (b - NB1) * BS + tid;
        if (n >= N) return;
        const float p[3] = {pos[3 * n], pos[3 * n + 1], pos[3 * n + 2]};
        v2f u[16], v[16];
#pragma unroll
        for (int g = 0; g < 16; ++g) {
            u[g] = *reinterpret_cast<const v2f*>(&ba[g * 2]);
            v2f z = {0.0f, 0.0f};
            v[g] = z;
        }
#pragma unroll
        for (int i = 0; i < 3; ++i) {
            const v2f f = {p[i], p[i]};
#pragma unroll
            for (int g = 0; g < 16; ++g) {
                const v2f wA = *reinterpret_cast<const v2f*>(&Wa[i * 32 + g * 2]);
                const v2f wB = *reinterpret_cast<const v2f*>(&Wa[(i + 3) * 32 + g * 2]);
                u[g] = __builtin_elementwise_fma(f, wA + wB, u[g]);
                v[g] = __builtin_elementwise_fma(f, wB, v[g]);
            }
        }
        uint4* Up = reinterpret_cast<uint4*>(Ubf + (size_t)n * 16);
        float4* Vp = reinterpret_cast<float4*>(V + (size_t)n * 32);
#pragma unroll
        for (int q = 0; q < 4; ++q) {
            uint4 o;
            o.x = cvt2(u[4 * q + 0].x, u[4 * q + 0].y);
            o.y = cvt2(u[4 * q + 1].x, u[4 * q + 1].y);
            o.z = cvt2(u[4 * q + 2].x, u[4 * q + 2].y);
            o.w = cvt2(u[4 * q + 3].x, u[4 * q + 3].y);
            Up[q] = o;
        }
#pragma unroll
        for (int q = 0; q < 8; ++q)
            Vp[q] = make_float4(v[2 * q].x, v[2 * q].y, v[2 * q + 1].x, v[2 * q + 1].y);
    } else {
        // pack per-lane B fragments (bf16 pairs) for both layers: 2 x 512 dw
        if (tid < 128) {
            const int layer = tid >> 6;
            const int t = tid & 63;
            const int lnp = t & 31;
            const int hp = t >> 5;
            const float* Wb = layer ? Wb4 : Wb2;
            unsigned* dst = WbtG + layer * 512 + t * 8;
#pragma unroll
            for (int q = 0; q < 4; ++q) {
                const int p = 4 * hp + q;
                dst[q] = cvt2(Wb[(2 * p) * 32 + lnp], Wb[(2 * p + 1) * 32 + lnp]);
                dst[4 + q] = cvt2(Wb[(2 * p + 16) * 32 + lnp], Wb[(2 * p + 17) * 32 + lnp]);
            }
        }
    }
}

// ---------------- pass 2a: per-(block,range) LOCAL prefixes + range totals --
__global__ __launch_bounds__(512) void off_scan_kernel(const int* __restrict__ blockHist,
                                                       int NB1, int NRP,
                                                       int* __restrict__ off,
                                                       int* __restrict__ total) {
    const int r = (blockIdx.x * 512 + threadIdx.x) >> 6;
    const int lane = threadIdx.x & 63;
    if (r >= NRP) return;
    int carry = 0;
    const int chunks = (NB1 + 63) / 64;
    for (int c = 0; c < chunks; ++c) {
        const int b = c * 64 + lane;
        const int v = (b < NB1) ? blockHist[b * NRP + r] : 0;
        int x = v;
#pragma unroll
        for (int d = 1; d < 64; d <<= 1) {
            int y = __shfl_up(x, d, 64);
            if (lane >= d) x += y;
        }
        if (b < NB1) off[b * NRP + r] = carry + (x - v);
        carry += __shfl(x, 63, 64);
    }
    if (lane == 0) total[r] = carry;
}

// ---------------- pass 2b: exclusive scan of totals (<=2048) -> rangeBase ---
__global__ __launch_bounds__(1024) void range_scan_kernel(const int* __restrict__ total,
                                                          int NRP, int* __restrict__ rangeBase) {
    __shared__ int s[2048];
    const int t = threadIdx.x;
    const int v0 = (t < NRP) ? total[t] : 0;
    const int v1 = (t + 1024 < NRP) ? total[t + 1024] : 0;
    s[t] = v0;
    s[t + 1024] = v1;
    __syncthreads();
    for (int off = 1; off < 2048; off <<= 1) {
        const int a0 = (t >= off) ? s[t - off] : 0;
        const int a1 = (t + 1024 >= off) ? s[t + 1024 - off] : 0;
        __syncthreads();
        s[t] += a0;
        s[t + 1024] += a1;
        __syncthreads();
    }
    if (t < NRP) rangeBase[t] = s[t] - v0;
    if (t + 1024 < NRP) rangeBase[t + 1024] = s[t + 1024] - v1;
}

// ---------------- pass 1b: LDS-ranked scatter into range buckets ------------
// Stages u32-packed edges (src | dstLocal<<20) + u16 range ids.
__global__ __launch_bounds__(BS) void bucket_scatter_kernel(
    const int* __restrict__ ei, int E, int NRP, const int* __restrict__ off,
    const int* __restrict__ rangeBase, unsigned* __restrict__ sedgeB) {
    __shared__ unsigned stage[K1_EDGES];      // 16 KB
    __shared__ unsigned short rng[K1_EDGES];  // 8 KB
    __shared__ unsigned short inv[K1_EDGES];  // 8 KB
    __shared__ int hist[2048], start[2048], cursor[2048];  // 24 KB
    __shared__ int ts[BS];
    const int tid = threadIdx.x;
    for (int r = tid; r < 2048; r += BS) hist[r] = 0;
    __syncthreads();
    const int base = blockIdx.x * K1_EDGES;
    const int M = min(K1_EDGES, E - base);
    for (int i = tid; i < M; i += BS) {
        const int src = ei[base + i];
        const int dst = ei[E + base + i];
        const int r = dst >> 6;
        stage[i] = (unsigned)src | ((unsigned)(dst & 63) << 20);
        rng[i] = (unsigned short)r;
        atomicAdd(&hist[r], 1);
    }
    __syncthreads();
    {
        const int i0 = tid * 8;
        int lv[8];
        int tsum = 0;
#pragma unroll
        for (int k = 0; k < 8; ++k) {
            lv[k] = hist[i0 + k];
            tsum += lv[k];
        }
        ts[tid] = tsum;
        __syncthreads();
        for (int off2 = 1; off2 < BS; off2 <<= 1) {
            int add = (tid >= off2) ? ts[tid - off2] : 0;
            __syncthreads();
            ts[tid] += add;
            __syncthreads();
        }
        int run = ts[tid] - tsum;
#pragma unroll
        for (int k = 0; k < 8; ++k) {
            start[i0 + k] = run;
            cursor[i0 + k] = run;
            run += lv[k];
        }
    }
    __syncthreads();
    for (int i = tid; i < M; i += BS) {
        const int pos = atomicAdd(&cursor[rng[i]], 1);
        inv[pos] = (unsigned short)i;
    }
    __syncthreads();
    const int* offb = off + blockIdx.x * NRP;
    for (int j = tid; j < M; j += BS) {
        const int i = inv[j];
        const int r = rng[i];
        sedgeB[rangeBase[r] + offb[r] + (j - start[r])] = stage[i];  // contiguous runs
    }
}

// ---------------- range-bucket edge kernel (64-dst ranges, 8 waves) ---------
// MODE 0: final layer — decode aggL, relu, write float out.
// MODE 1: fused prep — compute layer-2 U/V for this block's 64 nodes.
// Main loop = R23's proven no-spill codegen at the 85-reg budget (never
// request >6 waves/EU), with the scatter phase reworked: per-wave dst byte
// table + quad-collapsed atomics.
template <int MODE>
__global__ __launch_bounds__(EBS, 6) void edge_range_kernel(
    const unsigned* __restrict__ Ubf, const float4* __restrict__ V,
    const unsigned* __restrict__ sedgeB, const int* __restrict__ rangeBase,
    const int* __restrict__ total, const unsigned* __restrict__ WbtG,
    const float* __restrict__ bb, const float* __restrict__ pos,
    const float* __restrict__ Wa2, const float* __restrict__ ba2,
    unsigned* __restrict__ Ubf2, float* __restrict__ Vbuf2,
    float* __restrict__ out, int N) {
    __shared__ unsigned aggL[2048];             // [64 dst][32 ch], 8 KB
    __shared__ __align__(16) float4 vlds[576];  // [64 rows][9 f4] (8 used), 9 KB
    __shared__ unsigned dstw[8][16];            // per-wave dst byte table, 512 B

    const int tid = threadIdx.x;
    const int r = blockIdx.x;
    const int base = rangeBase[r];
    const int M = total[r];
    const int last = M - 1;

    const int l = tid & 63;
    const int w = tid >> 6;  // 0..7: wave w owns chunk edges [64w, 64w+64)
    const int half = l >> 5;
    const int ln = l & 31;

#pragma unroll
    for (int i = 0; i < 4; ++i) aggL[tid + i * EBS] = ORD_NEG_INF;

    // stage V rows [64r, 64r+64): coalesced, padded stride 9
    {
        const float4* Vg = V + ((size_t)r << 9);        // row 64r, 8 f4/row
        const int vmax = min(512, (N - (r << 6)) * 8);  // clamp at N
        if (tid < vmax) vlds[(tid >> 3) * 9 + (tid & 7)] = Vg[tid];
    }

    // B fragments: precomputed per-lane packed bf16 (L1-hot, 2 loads)
    const uint4 bu0 = *reinterpret_cast<const uint4*>(WbtG + l * 8);
    const uint4 bu1 = *reinterpret_cast<const uint4*>(WbtG + l * 8 + 4);
    const float bbn = bb[ln];
    __syncthreads();  // aggL init + V stage visible

    const int nch = (M + EBS - 1) >> 9;
    unsigned pk = 0;
    if (64 * w < M) pk = sedgeB[base + min(64 * w + l, last)];  // chunk-0 descs
    for (int c = 0; c < nch; ++c) {
        // prefetch next chunk's descriptors (wave-uniform participation)
        unsigned npk = 0;
        const int ncb = (c + 1) << 9;
        const bool nextAct = (c + 1 < nch) && (ncb + 64 * w < M);
        if (nextAct) npk = sedgeB[base + min(ncb + 64 * w + l, last)];
        if ((c << 9) + 64 * w < M) {  // this wave active this chunk
            // dst byte table for this wave's 64 edges (same-wave write/read:
            // lgkmcnt orders it, no barrier; proven in R22)
            reinterpret_cast<unsigned char*>(dstw[w])[l] = (unsigned char)(pk >> 20);

            const unsigned pkA = __shfl(pk, ln, 64);       // edge cb+64w+ln
            const unsigned pkB = __shfl(pk, 32 + ln, 64);  // edge cb+64w+32+ln
            uint4 au00, au01, au10, au11;
            {
                const uint4* Up = reinterpret_cast<const uint4*>(Ubf + (size_t)(pkA & SRC_MASK) * 16);
                const float4* Vr = &vlds[(pkA >> 20) * 9];
                au00 = mk_frag(Up[half], Vr[2 * half], Vr[2 * half + 1]);
                au01 = mk_frag(Up[2 + half], Vr[4 + 2 * half], Vr[5 + 2 * half]);
            }
            {
                const uint4* Up = reinterpret_cast<const uint4*>(Ubf + (size_t)(pkB & SRC_MASK) * 16);
                const float4* Vr = &vlds[(pkB >> 20) * 9];
                au10 = mk_frag(Up[half], Vr[2 * half], Vr[2 * half + 1]);
                au11 = mk_frag(Up[2 + half], Vr[4 + 2 * half], Vr[5 + 2 * half]);
            }

            f32x16 c0, c1;
#pragma unroll
            for (int i = 0; i < 16; ++i) {
                c0[i] = bbn;
                c1[i] = bbn;
            }
            c0 = __builtin_amdgcn_mfma_f32_32x32x16_bf16(
                __builtin_bit_cast(bf16x8, au00), __builtin_bit_cast(bf16x8, bu0), c0, 0, 0, 0);
            c0 = __builtin_amdgcn_mfma_f32_32x32x16_bf16(
                __builtin_bit_cast(bf16x8, au01), __builtin_bit_cast(bf16x8, bu1), c0, 0, 0, 0);
            c1 = __builtin_amdgcn_mfma_f32_32x32x16_bf16(
                __builtin_bit_cast(bf16x8, au10), __builtin_bit_cast(bf16x8, bu0), c1, 0, 0, 0);
            c1 = __builtin_amdgcn_mfma_f32_32x32x16_bf16(
                __builtin_bit_cast(bf16x8, au11), __builtin_bit_cast(bf16x8, bu1), c1, 0, 0, 0);

            // scatter-max. Group g covers C rows 4g..4g+3 = CONSECUTIVE
            // edges 8g+4h+{0..3}; their dsts are the 4 bytes of dw[2g+h]
            // (c0) / dw[8+2g+h] (c1) — wave-uniform per half -> the
            // all-same-dst test does not diverge within a half. Fast path
            // (deg~16 => ~80%): reduce 4 in-register, 1 ordenc, 1 atomic.
            const unsigned* dw = dstw[w];
#pragma unroll
            for (int g = 0; g < 4; ++g) {
                const unsigned p0 = dw[2 * g + half];
                const unsigned p1 = dw[8 + 2 * g + half];
                {
                    const float v0 = c0[4 * g + 0], v1 = c0[4 * g + 1];
                    const float v2 = c0[4 * g + 2], v3 = c0[4 * g + 3];
                    if (p0 == (p0 & 0xFFu) * 0x01010101u) {
                        const float m = fmaxf(fmaxf(v0, v1), fmaxf(v2, v3));
                        atomicMax(&aggL[((p0 & 0x3Fu) << 5) | ln], ordenc(m));
                    } else {
                        atomicMax(&aggL[(((p0 >> 0) & 0x3Fu) << 5) | ln], ordenc(v0));
                        atomicMax(&aggL[(((p0 >> 8) & 0x3Fu) << 5) | ln], ordenc(v1));
                        atomicMax(&aggL[(((p0 >> 16) & 0x3Fu) << 5) | ln], ordenc(v2));
                        atomicMax(&aggL[(((p0 >> 24) & 0x3Fu) << 5) | ln], ordenc(v3));
                    }
                }
                {
                    const float v0 = c1[4 * g + 0], v1 = c1[4 * g + 1];
                    const float v2 = c1[4 * g + 2], v3 = c1[4 * g + 3];
                    if (p1 == (p1 & 0xFFu) * 0x01010101u) {
                        const float m = fmaxf(fmaxf(v0, v1), fmaxf(v2, v3));
                        atomicMax(&aggL[((p1 & 0x3Fu) << 5) | ln], ordenc(m));
                    } else {
                        atomicMax(&aggL[(((p1 >> 0) & 0x3Fu) << 5) | ln], ordenc(v0));
                        atomicMax(&aggL[(((p1 >> 8) & 0x3Fu) << 5) | ln], ordenc(v1));
                        atomicMax(&aggL[(((p1 >> 16) & 0x3Fu) << 5) | ln], ordenc(v2));
                        atomicMax(&aggL[(((p1 >> 24) & 0x3Fu) << 5) | ln], ordenc(v3));
                    }
                }
            }
        }
        pk = npk;  // garbage if !nextAct, but then unused next iter
    }
    __syncthreads();

    if (MODE == 0) {
        // final writeout: 2048 values, 4 per thread, decode + relu -> float
        const int idx = tid * 4;
        const int node = (r << 6) + (idx >> 5);
        if (node < N) {
            float4 o;
            o.x = fmaxf(orddec(aggL[idx + 0]), 0.0f);
            o.y = fmaxf(orddec(aggL[idx + 1]), 0.0f);
            o.z = fmaxf(orddec(aggL[idx + 2]), 0.0f);
            o.w = fmaxf(orddec(aggL[idx + 3]), 0.0f);
            *reinterpret_cast<float4*>(out + (size_t)node * 32 + (idx & 31)) = o;
        }
    } else {
        // fused layer-2 prep: 8 threads per node, 4 channels each.
        const int node_l = tid >> 3;  // 0..63
        const int qq = tid & 7;       // channel group [4qq, 4qq+4)
        const int node = (r << 6) + node_l;
        if (node < N) {
            const unsigned* row = &aggL[node_l << 5];
            float h[32];
#pragma unroll
            for (int i = 0; i < 32; ++i) h[i] = fmaxf(orddec(row[i]), 0.0f);
            const float pp[3] = {pos[3 * node], pos[3 * node + 1], pos[3 * node + 2]};
            v2f u[2], v[2];
#pragma unroll
            for (int g = 0; g < 2; ++g) {
                u[g] = *reinterpret_cast<const v2f*>(&ba2[4 * qq + 2 * g]);
                v2f z = {0.0f, 0.0f};
                v[g] = z;
            }
#pragma unroll
            for (int i = 0; i < 32; ++i) {
                const v2f f = {h[i], h[i]};
#pragma unroll
                for (int g = 0; g < 2; ++g) {
                    const v2f wv =
                        *reinterpret_cast<const v2f*>(&Wa2[i * 32 + 4 * qq + 2 * g]);
                    u[g] = __builtin_elementwise_fma(f, wv, u[g]);
                }
            }
#pragma unroll
            for (int i = 0; i < 3; ++i) {
                const v2f f = {pp[i], pp[i]};
#pragma unroll
                for (int g = 0; g < 2; ++g) {
                    const v2f wv =
                        *reinterpret_cast<const v2f*>(&Wa2[(32 + i) * 32 + 4 * qq + 2 * g]);
                    u[g] = __builtin_elementwise_fma(f, wv, u[g]);
                    v[g] = __builtin_elementwise_fma(f, wv, v[g]);
                }
            }
            uint2 o;
            o.x = cvt2(u[0].x, u[0].y);
            o.y = cvt2(u[1].x, u[1].y);
            *reinterpret_cast<uint2*>(Ubf2 + (size_t)node * 16 + 2 * qq) = o;
            *reinterpret_cast<float4*>(Vbuf2 + (size_t)node * 32 + 4 * qq) =
                make_float4(v[0].x, v[0].y, v[1].x, v[1].y);
        }
    }
}

extern "C" void kernel_launch(void* const* d_in, const int* in_sizes, int n_in,
                              void* d_out, int out_size, void* d_ws, size_t ws_size,
                              hipStream_t stream) {
    const float* pos = (const float*)d_in[0];
    const int* ei = (const int*)d_in[1];
    const float* W1 = (const float*)d_in[3];
    const float* b1 = (const float*)d_in[4];
    const float* W2 = (const float*)d_in[5];
    const float* b2 = (const float*)d_in[6];
    const float* W3 = (const float*)d_in[7];
    const float* b3 = (const float*)d_in[8];
    const float* W4 = (const float*)d_in[9];
    const float* b4 = (const float*)d_in[10];

    const int E = in_sizes[1] / 2;
    const int N = in_sizes[0] / 3;
    const int n32 = N * 32;
    const int NPAD = ((N + BS - 1) / BS) * BS;
    const int NR = (N + RB - 1) / RB;       // ranges of 64 dsts
    const int NRP = ((NR + 15) / 16) * 16;  // padded (<= 2048)
    const int NB1 = (E + K1_EDGES - 1) / K1_EDGES;
    const int BH = NB1 * NRP;

    int* blockHist = (int*)d_ws;                      // BH
    int* off = blockHist + BH;                        // BH
    int* total = off + BH;                            // NRP
    int* rangeBase = total + NRP;                     // NRP
    unsigned* sedgeB = (unsigned*)(rangeBase + NRP);  // E (u32-packed edges)
    unsigned* Ubf = (unsigned*)(sedgeB + E);          // NPAD*16 (layer-1 U)
    float* Vbuf = (float*)(Ubf + (size_t)NPAD * 16);  // n32 (layer-1 V)
    unsigned* Ubf2 = (unsigned*)(Vbuf + n32);         // NPAD*16 (layer-2 U)
    float* Vbuf2 = (float*)(Ubf2 + (size_t)NPAD * 16);  // n32 (layer-2 V)
    unsigned* WbtG = (unsigned*)(Vbuf2 + n32);        // 1024 dw (2 layers x 512)

    const int NBn = (N + BS - 1) / BS;

    // fused: hist | prep1 | Wbt pack (mutually independent)
    setup_kernel<<<NB1 + NBn + 1, BS, 0, stream>>>(ei, E, NRP, blockHist, pos, W1, b1, Ubf,
                                                   Vbuf, N, NB1, NBn, W2, W4, WbtG);
    off_scan_kernel<<<(NRP * 64 + 511) / 512, 512, 0, stream>>>(blockHist, NB1, NRP, off,
                                                                total);
    range_scan_kernel<<<1, 1024, 0, stream>>>(total, NRP, rangeBase);
    bucket_scatter_kernel<<<NB1, BS, 0, stream>>>(ei, E, NRP, off, rangeBase, sedgeB);

    // --- layer 1 (fused layer-2 prep in epilogue) ---
    edge_range_kernel<1><<<NR, EBS, 0, stream>>>(Ubf, (const float4*)Vbuf, sedgeB, rangeBase,
                                                 total, WbtG, b2, pos, W3, b3, Ubf2, Vbuf2,
                                                 nullptr, N);
    // --- layer 2 (final) ---
    edge_range_kernel<0><<<NR, EBS, 0, stream>>>(Ubf2, (const float4*)Vbuf2, sedgeB,
                                                 rangeBase, total, WbtG + 512, b4, nullptr,
                                                 nullptr, nullptr, nullptr, nullptr,
                                                 (float*)d_out, N);
}